// Round 3
// baseline (264.367 us; speedup 1.0000x reference)
//
#include <hip/hip_runtime.h>
#include <hip/hip_bf16.h>

typedef __attribute__((ext_vector_type(4))) float floatx4;
typedef __attribute__((ext_vector_type(8))) short short8;

__device__ __forceinline__ unsigned short f2bf(float f) {
    union { float f; unsigned int i; } v; v.f = f;
    unsigned int r = (v.i + 0x7FFFu + ((v.i >> 16) & 1u)) >> 16;
    return (unsigned short)r;
}

__device__ __forceinline__ uint2 pack_bf16x4(float4 v) {
    __hip_bfloat162 lo = __float22bfloat162_rn(make_float2(v.x, v.y));
    __hip_bfloat162 hi = __float22bfloat162_rn(make_float2(v.z, v.w));
    uint2 r;
    __builtin_memcpy(&r.x, &lo, 4);
    __builtin_memcpy(&r.y, &hi, 4);
    return r;
}

// ---------------- prep: phi (1024x24) and W (256x256) -> bf16 MFMA B-frag order
// phiF: [ks 0..31][nt 0..1][lane 0..63][j 0..7]; B[k][n], k=ks*32+quad*8+j, n=nt*16+col
// WF  : [ntile 0..15][ks 0..7][lane 0..63][j 0..7]; B[k][n]=W[n][k]
__global__ void mhc_prep(const float* __restrict__ phi, const float* __restrict__ W,
                         unsigned short* __restrict__ phiF, unsigned short* __restrict__ WF) {
    int e = blockIdx.x * 256 + threadIdx.x;
    if (e < 32768) {
        int j = e & 7, lane = (e >> 3) & 63, nt = (e >> 9) & 1, ks = e >> 10;
        int n = nt * 16 + (lane & 15);
        int k = ks * 32 + ((lane >> 4) & 3) * 8 + j;
        phiF[e] = f2bf((n < 24) ? phi[k * 24 + n] : 0.0f);
    } else {
        int e2 = e - 32768;
        int j = e2 & 7, lane = (e2 >> 3) & 63, ks = (e2 >> 9) & 7, nt = e2 >> 12;
        int n = nt * 16 + (lane & 15);
        int k = ks * 32 + ((lane >> 4) & 3) * 8 + j;
        WF[e2] = f2bf(W[n * 256 + k]);
    }
}

// ---------------- main fused kernel: 16 tokens/block, x register-resident ----
#define XS_STRIDE 1032   // bf16, phase-1 A-frags: col*2064B, 16B-aligned, 2-way banks (free)
#define XIN_STRIDE 264   // bf16
#define FO_STRIDE 260    // fp32
#define CO_STRIDE 24     // fp32, 96B

__global__ __launch_bounds__(256, 3) void mhc_main(
    const float* __restrict__ x, const float* __restrict__ bias,
    const float* __restrict__ s_ap, const float* __restrict__ s_apo,
    const float* __restrict__ s_ar,
    const unsigned short* __restrict__ phiF, const unsigned short* __restrict__ WF,
    float* __restrict__ out)
{
    // region0: xs (phase 0-1) overlaid by xin+fout (phase 3-5)
    __shared__ __align__(16) unsigned char smem[16 * XS_STRIDE * 2];      // 33024 B
    __shared__ __align__(16) float lgp[2][16 * CO_STRIDE];                // 3072 B
    __shared__ __align__(16) float lgy[16 * CO_STRIDE];                   // 1536 B
    __shared__ __align__(16) float coef[16 * CO_STRIDE];                  // 1536 B

    unsigned short* xs  = (unsigned short*)smem;
    unsigned short* xin = (unsigned short*)smem;                // bytes 0..8447
    float*          fo  = (float*)(smem + 16 * XIN_STRIDE * 2); // bytes 8448..25087

    const int t = threadIdx.x;
    const int lane = t & 63;
    const int w = t >> 6;
    const int quad = lane >> 4;
    const int col = lane & 15;
    const int tok0 = w * 4;
    const int c4 = lane * 4;
    const long base = (long)blockIdx.x * 16384;

    // ---- phase 0: x -> registers (fp32) + bf16 LDS A-staging ----
    float4 xr[4][4];   // [tk][i] = x[tok0+tk][i][c4..c4+3]
    #pragma unroll
    for (int tk = 0; tk < 4; ++tk)
        #pragma unroll
        for (int i = 0; i < 4; ++i)
            xr[tk][i] = *reinterpret_cast<const float4*>(
                x + base + (long)(tok0 + tk) * 1024 + i * 256 + c4);
    #pragma unroll
    for (int tk = 0; tk < 4; ++tk)
        #pragma unroll
        for (int i = 0; i < 4; ++i)
            *reinterpret_cast<uint2*>(&xs[(tok0 + tk) * XS_STRIDE + i * 256 + c4]) =
                pack_bf16x4(xr[tk][i]);
    __syncthreads();

    // ---- phase 1: logits, split-k over wave pairs (waves 0,1: ks 0-15; 2,3: ks 16-31) ----
    {
        int nt = w & 1, half = w >> 1;
        floatx4 acc = {0.0f, 0.0f, 0.0f, 0.0f};
        #pragma unroll
        for (int kk = 0; kk < 16; ++kk) {
            int ks = half * 16 + kk;
            short8 a = *reinterpret_cast<const short8*>(&xs[col * XS_STRIDE + ks * 32 + quad * 8]);
            short8 b = *reinterpret_cast<const short8*>(&phiF[(ks * 2 + nt) * 512 + lane * 8]);
            acc = __builtin_amdgcn_mfma_f32_16x16x32_bf16(a, b, acc, 0, 0, 0);
        }
        int n = nt * 16 + col;
        if (n < 24) {
            #pragma unroll
            for (int r = 0; r < 4; ++r)
                lgp[half][(quad * 4 + r) * CO_STRIDE + n] = acc[r];
        }
    }
    __syncthreads();

    // ---- phase 2a: rms-norm + gates (16 lanes/token) ----
    {
        int tok = t >> 4, p = t & 15;
        float ya = lgp[0][tok * CO_STRIDE + p] + lgp[1][tok * CO_STRIDE + p];
        float yb = (p < 8) ? (lgp[0][tok * CO_STRIDE + 16 + p] + lgp[1][tok * CO_STRIDE + 16 + p])
                           : 0.0f;
        float s = ya * ya + yb * yb;
        s += __shfl_xor(s, 1); s += __shfl_xor(s, 2);
        s += __shfl_xor(s, 4); s += __shfl_xor(s, 8);
        float rinv = __builtin_amdgcn_rsqf(s * (1.0f / 24.0f) + 1e-6f);
        float yp = ya * rinv + bias[p];
        lgy[tok * CO_STRIDE + p] = yp;
        if (p < 8) {
            lgy[tok * CO_STRIDE + 16 + p] = yb * rinv + bias[16 + p];
            float a = (p < 4) ? s_ap[0] : s_apo[0];
            float h = __builtin_amdgcn_rcpf(1.0f + __builtin_amdgcn_exp2f(-a * yp * 1.44269504f));
            if (p >= 4) h *= 2.0f;
            coef[tok * CO_STRIDE + p] = h;
        }
    }
    __syncthreads();

    // ---- phase 2b: Sinkhorn, thread (tok, o) owns P row o as float4 ----
    if ((t & 15) < 4) {
        int tok = t >> 4, o = t & 3;
        float arl = s_ar[0] * 1.44269504f;
        float4 yv = *reinterpret_cast<const float4*>(&lgy[tok * CO_STRIDE + 8 + o * 4]);
        float4 P;
        P.x = __builtin_amdgcn_exp2f(arl * yv.x);
        P.y = __builtin_amdgcn_exp2f(arl * yv.y);
        P.z = __builtin_amdgcn_exp2f(arl * yv.z);
        P.w = __builtin_amdgcn_exp2f(arl * yv.w);
        #pragma unroll 1
        for (int it = 0; it < 20; ++it) {
            float ri = __builtin_amdgcn_rcpf(P.x + P.y + P.z + P.w + 1e-6f);
            P.x *= ri; P.y *= ri; P.z *= ri; P.w *= ri;
            float cx = P.x + __shfl_xor(P.x, 1); cx += __shfl_xor(cx, 2);
            float cy = P.y + __shfl_xor(P.y, 1); cy += __shfl_xor(cy, 2);
            float cz = P.z + __shfl_xor(P.z, 1); cz += __shfl_xor(cz, 2);
            float cw = P.w + __shfl_xor(P.w, 1); cw += __shfl_xor(cw, 2);
            P.x *= __builtin_amdgcn_rcpf(cx + 1e-6f);
            P.y *= __builtin_amdgcn_rcpf(cy + 1e-6f);
            P.z *= __builtin_amdgcn_rcpf(cz + 1e-6f);
            P.w *= __builtin_amdgcn_rcpf(cw + 1e-6f);
        }
        *reinterpret_cast<float4*>(&coef[tok * CO_STRIDE + 8 + o * 4]) = P;
    }

    // ---- phase 3: x_in from registers (hpre written in 2a by same wave) ----
    #pragma unroll
    for (int tk = 0; tk < 4; ++tk) {
        const float* cb = &coef[(tok0 + tk) * CO_STRIDE];
        float hx = cb[0], hy = cb[1], hz = cb[2], hw = cb[3];
        float4 xi;
        xi.x = hx * xr[tk][0].x + hy * xr[tk][1].x + hz * xr[tk][2].x + hw * xr[tk][3].x;
        xi.y = hx * xr[tk][0].y + hy * xr[tk][1].y + hz * xr[tk][2].y + hw * xr[tk][3].y;
        xi.z = hx * xr[tk][0].z + hy * xr[tk][1].z + hz * xr[tk][2].z + hw * xr[tk][3].z;
        xi.w = hx * xr[tk][0].w + hy * xr[tk][1].w + hz * xr[tk][2].w + hw * xr[tk][3].w;
        *reinterpret_cast<uint2*>(&xin[(tok0 + tk) * XIN_STRIDE + c4]) = pack_bf16x4(xi);
    }
    __syncthreads();

    // ---- phase 4: f_out = Xin(16x256) @ W^T via MFMA; wave w -> ntiles 4w..4w+3 ----
    {
        short8 afr[8];
        #pragma unroll
        for (int ks = 0; ks < 8; ++ks)
            afr[ks] = *reinterpret_cast<const short8*>(&xin[col * XIN_STRIDE + ks * 32 + quad * 8]);
        #pragma unroll
        for (int nt = 0; nt < 4; ++nt) {
            floatx4 acc = {0.0f, 0.0f, 0.0f, 0.0f};
            int ntile = w * 4 + nt;
            #pragma unroll
            for (int ks = 0; ks < 8; ++ks) {
                short8 b = *reinterpret_cast<const short8*>(&WF[(ntile * 8 + ks) * 512 + lane * 8]);
                acc = __builtin_amdgcn_mfma_f32_16x16x32_bf16(afr[ks], b, acc, 0, 0, 0);
            }
            #pragma unroll
            for (int r = 0; r < 4; ++r)
                fo[(quad * 4 + r) * FO_STRIDE + ntile * 16 + col] = acc[r];
        }
    }
    __syncthreads();

    // ---- phase 5: out[tok][o][c] = sum_i P[o][i] x[tok][i][c] + hpost[o] f_out[tok][c] ----
    #pragma unroll
    for (int tk = 0; tk < 4; ++tk) {
        int tok = tok0 + tk;
        const float* cb = &coef[tok * CO_STRIDE];
        float4 f   = *reinterpret_cast<const float4*>(&fo[tok * FO_STRIDE + c4]);
        float4 hpo = *reinterpret_cast<const float4*>(cb + 4);
        float4 P0  = *reinterpret_cast<const float4*>(cb + 8);
        float4 P1  = *reinterpret_cast<const float4*>(cb + 12);
        float4 P2  = *reinterpret_cast<const float4*>(cb + 16);
        float4 P3  = *reinterpret_cast<const float4*>(cb + 20);
        float* ob = out + base + (long)tok * 1024 + c4;
        floatx4 o0, o1, o2, o3;
        o0.x = P0.x*xr[tk][0].x + P0.y*xr[tk][1].x + P0.z*xr[tk][2].x + P0.w*xr[tk][3].x + hpo.x*f.x;
        o0.y = P0.x*xr[tk][0].y + P0.y*xr[tk][1].y + P0.z*xr[tk][2].y + P0.w*xr[tk][3].y + hpo.x*f.y;
        o0.z = P0.x*xr[tk][0].z + P0.y*xr[tk][1].z + P0.z*xr[tk][2].z + P0.w*xr[tk][3].z + hpo.x*f.z;
        o0.w = P0.x*xr[tk][0].w + P0.y*xr[tk][1].w + P0.z*xr[tk][2].w + P0.w*xr[tk][3].w + hpo.x*f.w;
        o1.x = P1.x*xr[tk][0].x + P1.y*xr[tk][1].x + P1.z*xr[tk][2].x + P1.w*xr[tk][3].x + hpo.y*f.x;
        o1.y = P1.x*xr[tk][0].y + P1.y*xr[tk][1].y + P1.z*xr[tk][2].y + P1.w*xr[tk][3].y + hpo.y*f.y;
        o1.z = P1.x*xr[tk][0].z + P1.y*xr[tk][1].z + P1.z*xr[tk][2].z + P1.w*xr[tk][3].z + hpo.y*f.z;
        o1.w = P1.x*xr[tk][0].w + P1.y*xr[tk][1].w + P1.z*xr[tk][2].w + P1.w*xr[tk][3].w + hpo.y*f.w;
        o2.x = P2.x*xr[tk][0].x + P2.y*xr[tk][1].x + P2.z*xr[tk][2].x + P2.w*xr[tk][3].x + hpo.z*f.x;
        o2.y = P2.x*xr[tk][0].y + P2.y*xr[tk][1].y + P2.z*xr[tk][2].y + P2.w*xr[tk][3].y + hpo.z*f.y;
        o2.z = P2.x*xr[tk][0].z + P2.y*xr[tk][1].z + P2.z*xr[tk][2].z + P2.w*xr[tk][3].z + hpo.z*f.z;
        o2.w = P2.x*xr[tk][0].w + P2.y*xr[tk][1].w + P2.z*xr[tk][2].w + P2.w*xr[tk][3].w + hpo.z*f.w;
        o3.x = P3.x*xr[tk][0].x + P3.y*xr[tk][1].x + P3.z*xr[tk][2].x + P3.w*xr[tk][3].x + hpo.w*f.x;
        o3.y = P3.x*xr[tk][0].y + P3.y*xr[tk][1].y + P3.z*xr[tk][2].y + P3.w*xr[tk][3].y + hpo.w*f.y;
        o3.z = P3.x*xr[tk][0].z + P3.y*xr[tk][1].z + P3.z*xr[tk][2].z + P3.w*xr[tk][3].z + hpo.w*f.z;
        o3.w = P3.x*xr[tk][0].w + P3.y*xr[tk][1].w + P3.z*xr[tk][2].w + P3.w*xr[tk][3].w + hpo.w*f.w;
        __builtin_nontemporal_store(o0, reinterpret_cast<floatx4*>(ob));
        __builtin_nontemporal_store(o1, reinterpret_cast<floatx4*>(ob + 256));
        __builtin_nontemporal_store(o2, reinterpret_cast<floatx4*>(ob + 512));
        __builtin_nontemporal_store(o3, reinterpret_cast<floatx4*>(ob + 768));
    }
}

extern "C" void kernel_launch(void* const* d_in, const int* in_sizes, int n_in,
                              void* d_out, int out_size, void* d_ws, size_t ws_size,
                              hipStream_t stream) {
    const float* x    = (const float*)d_in[0];
    const float* phi  = (const float*)d_in[1];
    const float* bias = (const float*)d_in[2];
    const float* ap   = (const float*)d_in[3];
    const float* apo  = (const float*)d_in[4];
    const float* ar   = (const float*)d_in[5];
    const float* W    = (const float*)d_in[6];
    float* out = (float*)d_out;

    unsigned short* phiF = (unsigned short*)d_ws;           // 32768 bf16
    unsigned short* WF   = (unsigned short*)d_ws + 32768;   // 65536 bf16

    mhc_prep<<<384, 256, 0, stream>>>(phi, W, phiF, WF);
    mhc_main<<<2048, 256, 0, stream>>>(x, bias, ap, apo, ar, phiF, WF, out);
}